// Round 1
// baseline (1399.334 us; speedup 1.0000x reference)
//
#include <hip/hip_runtime.h>

typedef __attribute__((ext_vector_type(8))) short short8;
typedef __attribute__((ext_vector_type(4))) float f32x4;

__device__ __forceinline__ unsigned short f2bf(float f) {
  unsigned int u = __builtin_bit_cast(unsigned int, f);
  u += 0x7fffu + ((u >> 16) & 1u);
  return (unsigned short)(u >> 16);
}
__device__ __forceinline__ float bf2f(unsigned short h) {
  unsigned int u = ((unsigned int)h) << 16;
  return __builtin_bit_cast(float, u);
}

// ---------------- cast fp32 -> bf16 (vectorized) ----------------
__global__ __launch_bounds__(256) void cast_kernel(const float* __restrict__ in,
                                                   unsigned short* __restrict__ out, int n4) {
  int idx = blockIdx.x * 256 + threadIdx.x;
  if (idx >= n4) return;
  const float4 v = ((const float4*)in)[idx];
  ushort4 o;
  o.x = f2bf(v.x); o.y = f2bf(v.y); o.z = f2bf(v.z); o.w = f2bf(v.w);
  ((ushort4*)out)[idx] = o;
}

// ---------------- transpose + cast: in (K x N fp32, row-major) -> out (N x K bf16) ----------------
__global__ __launch_bounds__(256) void transpose_cast_kernel(const float* __restrict__ in,
                                                             unsigned short* __restrict__ out,
                                                             int K, int N) {
  __shared__ float tile[64][65];
  const int kb = blockIdx.x * 64, nb = blockIdx.y * 64;
  const int tid = threadIdx.x;
  const int r = tid >> 4;          // 0..15
  const int c = (tid & 15) * 4;    // 0..60
#pragma unroll
  for (int i = 0; i < 4; i++) {
    const float4 v = *(const float4*)(in + (size_t)(kb + r + i * 16) * N + nb + c);
    tile[r + i * 16][c + 0] = v.x;
    tile[r + i * 16][c + 1] = v.y;
    tile[r + i * 16][c + 2] = v.z;
    tile[r + i * 16][c + 3] = v.w;
  }
  __syncthreads();
#pragma unroll
  for (int i = 0; i < 4; i++) {
    int n = r + i * 16;
    ushort4 o;
    o.x = f2bf(tile[c + 0][n]);
    o.y = f2bf(tile[c + 1][n]);
    o.z = f2bf(tile[c + 2][n]);
    o.w = f2bf(tile[c + 3][n]);
    *(ushort4*)(out + (size_t)(nb + n) * K + kb + c) = o;
  }
}

// ---------------- GEMM: C(MxN) = A(MxK,bf16,row-major) @ BT(NxK,bf16,row-major)^T ----------------
template <bool F32OUT>
__global__ __launch_bounds__(256, 2) void gemm_kernel(const unsigned short* __restrict__ A,
                                                      const unsigned short* __restrict__ BT,
                                                      void* __restrict__ C, int M, int N, int K) {
  __shared__ unsigned short As[128][72];  // +8 pad: 2-way bank aliasing only (free)
  __shared__ unsigned short Bs[128][72];
  const int m0 = blockIdx.x * 128, n0 = blockIdx.y * 128;
  const int tid = threadIdx.x;
  const int wave = tid >> 6, lane = tid & 63;
  const int wm = (wave & 1) * 64, wn = (wave >> 1) * 64;
  const int lr = lane & 15, kg = lane >> 4;
  const int sr = tid >> 3;        // 0..31
  const int sc = (tid & 7) * 8;   // 0..56
  f32x4 acc[4][4] = {};
  for (int k0 = 0; k0 < K; k0 += 64) {
#pragma unroll
    for (int i = 0; i < 4; i++) {
      int row = sr + i * 32;
      *(short8*)&As[row][sc] = *(const short8*)(A + (size_t)(m0 + row) * K + k0 + sc);
      *(short8*)&Bs[row][sc] = *(const short8*)(BT + (size_t)(n0 + row) * K + k0 + sc);
    }
    __syncthreads();
#pragma unroll
    for (int ks = 0; ks < 2; ks++) {
      short8 af[4], bfg[4];
#pragma unroll
      for (int mi = 0; mi < 4; mi++) af[mi] = *(const short8*)&As[wm + mi * 16 + lr][ks * 32 + kg * 8];
#pragma unroll
      for (int ni = 0; ni < 4; ni++) bfg[ni] = *(const short8*)&Bs[wn + ni * 16 + lr][ks * 32 + kg * 8];
#pragma unroll
      for (int mi = 0; mi < 4; mi++)
#pragma unroll
        for (int ni = 0; ni < 4; ni++)
          acc[mi][ni] = __builtin_amdgcn_mfma_f32_16x16x32_bf16(af[mi], bfg[ni], acc[mi][ni], 0, 0, 0);
    }
    __syncthreads();
  }
  // C/D layout: col = lane&15, row = (lane>>4)*4 + reg (m89-verified)
#pragma unroll
  for (int mi = 0; mi < 4; mi++)
#pragma unroll
    for (int ni = 0; ni < 4; ni++)
#pragma unroll
      for (int r2 = 0; r2 < 4; r2++) {
        int m = m0 + wm + mi * 16 + kg * 4 + r2;
        int n = n0 + wn + ni * 16 + lr;
        float v = acc[mi][ni][r2];
        if (F32OUT)
          ((float*)C)[(size_t)m * N + n] = v;
        else
          ((unsigned short*)C)[(size_t)m * N + n] = f2bf(v);
      }
}

// ---------------- RoPE in-place on bf16 projected Q or K ----------------
__global__ __launch_bounds__(256) void rope_kernel(unsigned short* __restrict__ buf, int nheads, int total) {
  int idx = blockIdx.x * 256 + threadIdx.x;
  if (idx >= total) return;
  int i = idx & 63;
  int h = (idx >> 6) % nheads;
  int row = idx / (64 * nheads);
  int pos = row & 1023;
  float invf = exp2f(-(float)(2 * i) * (13.287712379549449f / 128.f));  // 10000^(-2i/128)
  float ang = (float)pos * invf;
  float s, c;
  __sincosf(ang, &s, &c);
  unsigned short* p = buf + (size_t)row * ((size_t)nheads * 128) + h * 128;
  float x1 = bf2f(p[i]), x2 = bf2f(p[i + 64]);
  p[i] = f2bf(x1 * c - x2 * s);
  p[i + 64] = f2bf(x2 * c + x1 * s);
}

// ---------------- Flash attention: BQ=64 (16 rows/wave), BK=64, D=128 ----------------
__global__ __launch_bounds__(256, 2) void flash_kernel(const unsigned short* __restrict__ Q,
                                                       const unsigned short* __restrict__ Kbuf,
                                                       const unsigned short* __restrict__ Vbuf,
                                                       const float* __restrict__ mask,
                                                       unsigned short* __restrict__ Ctx) {
  __shared__ unsigned short Ks[64][136];    // [kpos][d], +8 pad
  __shared__ unsigned short Vt[128][64];    // [d][kpos], XOR-swizzled columns
  __shared__ unsigned short Ps[4][16][72];  // per-wave P tile [q][kpos], +8 pad
  const int qb = blockIdx.x, h = blockIdx.y, b = blockIdx.z;
  const int hkv = h >> 2;
  const int tid = threadIdx.x, wave = tid >> 6, lane = tid & 63;
  const int lr = lane & 15, kg = lane >> 4;
  const int q0 = qb * 64 + wave * 16;

  short8 qf[4];
  {
    const unsigned short* qp = Q + (size_t)(b * 1024 + q0 + lr) * 4096 + h * 128 + kg * 8;
#pragma unroll
    for (int ks = 0; ks < 4; ks++) qf[ks] = *(const short8*)(qp + ks * 32);
  }
  f32x4 o[8] = {};
  float mrow_[4], lrow_[4];
#pragma unroll
  for (int r2 = 0; r2 < 4; r2++) { mrow_[r2] = -1e30f; lrow_[r2] = 0.f; }
  const float* mbase = mask + (size_t)b * 1024 * 1024;

  for (int k0 = 0; k0 < 1024; k0 += 64) {
    {
      int row = tid >> 4, cc = (tid & 15) * 8;
#pragma unroll
      for (int i = 0; i < 4; i++)
        *(short8*)&Ks[row + i * 16][cc] =
            *(const short8*)(Kbuf + (size_t)(b * 1024 + k0 + row + i * 16) * 1024 + hkv * 128 + cc);
#pragma unroll
      for (int pass = 0; pass < 2; pass++) {
        int kp = (tid >> 4) * 2 + pass * 32;
        int d0 = (tid & 15) * 8;
        short8 v0 = *(const short8*)(Vbuf + (size_t)(b * 1024 + k0 + kp) * 1024 + hkv * 128 + d0);
        short8 v1 = *(const short8*)(Vbuf + (size_t)(b * 1024 + k0 + kp + 1) * 1024 + hkv * 128 + d0);
#pragma unroll
        for (int j = 0; j < 8; j++) {
          int d = d0 + j;
          int kk = kp ^ (((d >> 3) & 7) << 3);
          unsigned int pack = (unsigned int)(unsigned short)v0[j] | ((unsigned int)(unsigned short)v1[j] << 16);
          *(unsigned int*)&Vt[d][kk] = pack;
        }
      }
    }
    __syncthreads();

    f32x4 s[4] = {};
#pragma unroll
    for (int ks = 0; ks < 4; ks++)
#pragma unroll
      for (int nf = 0; nf < 4; nf++) {
        short8 kf = *(const short8*)&Ks[nf * 16 + lr][ks * 32 + kg * 8];
        s[nf] = __builtin_amdgcn_mfma_f32_16x16x32_bf16(qf[ks], kf, s[nf], 0, 0, 0);
      }

    float sv[4][4];
#pragma unroll
    for (int nf = 0; nf < 4; nf++)
#pragma unroll
      for (int r2 = 0; r2 < 4; r2++) {
        float v = s[nf][r2] * 0.08838834764831845f;  // 1/sqrt(128)
        int qq = q0 + kg * 4 + r2;
        int kx = k0 + nf * 16 + lr;
        float mv = mbase[(size_t)qq * 1024 + kx];
        sv[nf][r2] = (mv != 0.f) ? v : -1e9f;
      }

    float rmax[4];
#pragma unroll
    for (int r2 = 0; r2 < 4; r2++) {
      float v = fmaxf(fmaxf(sv[0][r2], sv[1][r2]), fmaxf(sv[2][r2], sv[3][r2]));
#pragma unroll
      for (int off = 1; off < 16; off <<= 1) v = fmaxf(v, __shfl_xor(v, off, 16));
      rmax[r2] = v;
    }
    float alpha[4];
#pragma unroll
    for (int r2 = 0; r2 < 4; r2++) {
      float mnew = fmaxf(mrow_[r2], rmax[r2]);
      alpha[r2] = __expf(mrow_[r2] - mnew);
      mrow_[r2] = mnew;
    }
    float rsum[4] = {0.f, 0.f, 0.f, 0.f};
    unsigned short pb[4][4];
#pragma unroll
    for (int nf = 0; nf < 4; nf++)
#pragma unroll
      for (int r2 = 0; r2 < 4; r2++) {
        float p = __expf(sv[nf][r2] - mrow_[r2]);
        rsum[r2] += p;
        pb[nf][r2] = f2bf(p);
      }
#pragma unroll
    for (int r2 = 0; r2 < 4; r2++) {
      float v = rsum[r2];
#pragma unroll
      for (int off = 1; off < 16; off <<= 1) v += __shfl_xor(v, off, 16);
      lrow_[r2] = lrow_[r2] * alpha[r2] + v;
    }
#pragma unroll
    for (int nf2 = 0; nf2 < 8; nf2++)
#pragma unroll
      for (int r2 = 0; r2 < 4; r2++) o[nf2][r2] *= alpha[r2];

#pragma unroll
    for (int nf = 0; nf < 4; nf++)
#pragma unroll
      for (int r2 = 0; r2 < 4; r2++) Ps[wave][kg * 4 + r2][nf * 16 + lr] = pb[nf][r2];

#pragma unroll
    for (int ks2 = 0; ks2 < 2; ks2++) {
      short8 pf = *(const short8*)&Ps[wave][lr][ks2 * 32 + kg * 8];
#pragma unroll
      for (int nf = 0; nf < 8; nf++) {
        int d = nf * 16 + lr;
        int kk = (ks2 * 32 + kg * 8) ^ (((d >> 3) & 7) << 3);
        short8 vf = *(const short8*)&Vt[d][kk];
        o[nf] = __builtin_amdgcn_mfma_f32_16x16x32_bf16(pf, vf, o[nf], 0, 0, 0);
      }
    }
    __syncthreads();
  }

#pragma unroll
  for (int nf = 0; nf < 8; nf++)
#pragma unroll
    for (int r2 = 0; r2 < 4; r2++) {
      float v = o[nf][r2] / lrow_[r2];
      int qq = q0 + kg * 4 + r2;
      int d = nf * 16 + lr;
      Ctx[(size_t)(b * 1024 + qq) * 4096 + h * 128 + d] = f2bf(v);
    }
}

extern "C" void kernel_launch(void* const* d_in, const int* in_sizes, int n_in,
                              void* d_out, int out_size, void* d_ws, size_t ws_size,
                              hipStream_t stream) {
  const float* query = (const float*)d_in[0];
  const float* key   = (const float*)d_in[1];
  const float* value = (const float*)d_in[2];
  const float* mask  = (const float*)d_in[3];
  const float* wq    = (const float*)d_in[4];
  const float* wk    = (const float*)d_in[5];
  const float* wv    = (const float*)d_in[6];
  const float* wo    = (const float*)d_in[7];
  float* out = (float*)d_out;

  char* ws = (char*)d_ws;
  size_t off = 0;
  auto alloc = [&](size_t elems) {
    unsigned short* p = (unsigned short*)(ws + off);
    off += ((elems * 2 + 255) / 256) * 256;
    return p;
  };
  unsigned short* qbf = alloc((size_t)2048 * 4096);
  unsigned short* kbf = alloc((size_t)2048 * 4096);
  unsigned short* vbf = alloc((size_t)2048 * 4096);
  unsigned short* wqT = alloc((size_t)4096 * 4096);
  unsigned short* wkT = alloc((size_t)1024 * 4096);
  unsigned short* wvT = alloc((size_t)1024 * 4096);
  unsigned short* woT = alloc((size_t)4096 * 4096);
  unsigned short* Qb  = alloc((size_t)2048 * 4096);
  unsigned short* Kb  = alloc((size_t)2048 * 1024);
  unsigned short* Vb  = alloc((size_t)2048 * 1024);
  unsigned short* Ctx = qbf;  // reuse: qbf dead after Q projection

  cast_kernel<<<8192, 256, 0, stream>>>(query, qbf, 2048 * 4096 / 4);
  cast_kernel<<<8192, 256, 0, stream>>>(key, kbf, 2048 * 4096 / 4);
  cast_kernel<<<8192, 256, 0, stream>>>(value, vbf, 2048 * 4096 / 4);
  transpose_cast_kernel<<<dim3(64, 64), 256, 0, stream>>>(wq, wqT, 4096, 4096);
  transpose_cast_kernel<<<dim3(64, 16), 256, 0, stream>>>(wk, wkT, 4096, 1024);
  transpose_cast_kernel<<<dim3(64, 16), 256, 0, stream>>>(wv, wvT, 4096, 1024);
  transpose_cast_kernel<<<dim3(64, 64), 256, 0, stream>>>(wo, woT, 4096, 4096);

  gemm_kernel<false><<<dim3(16, 32), 256, 0, stream>>>(qbf, wqT, Qb, 2048, 4096, 4096);
  gemm_kernel<false><<<dim3(16, 8), 256, 0, stream>>>(kbf, wkT, Kb, 2048, 1024, 4096);
  gemm_kernel<false><<<dim3(16, 8), 256, 0, stream>>>(vbf, wvT, Vb, 2048, 1024, 4096);

  rope_kernel<<<(2048 * 32 * 64) / 256, 256, 0, stream>>>(Qb, 32, 2048 * 32 * 64);
  rope_kernel<<<(2048 * 8 * 64) / 256, 256, 0, stream>>>(Kb, 8, 2048 * 8 * 64);

  flash_kernel<<<dim3(16, 32, 2), 256, 0, stream>>>(Qb, Kb, Vb, mask, Ctx);

  gemm_kernel<true><<<dim3(16, 32), 256, 0, stream>>>(Ctx, woT, out, 2048, 4096, 4096);

  (void)in_sizes; (void)n_in; (void)out_size; (void)ws_size;
}

// Round 2
// 747.413 us; speedup vs baseline: 1.8722x; 1.8722x over previous
//
#include <hip/hip_runtime.h>

typedef __attribute__((ext_vector_type(8))) short short8;
typedef __attribute__((ext_vector_type(4))) float f32x4;

__device__ __forceinline__ unsigned short f2bf(float f) {
  unsigned int u = __builtin_bit_cast(unsigned int, f);
  u += 0x7fffu + ((u >> 16) & 1u);
  return (unsigned short)(u >> 16);
}
__device__ __forceinline__ float bf2f(unsigned short h) {
  unsigned int u = ((unsigned int)h) << 16;
  return __builtin_bit_cast(float, u);
}

// async global->LDS, 16B per lane; lds dest = wave-uniform base + lane*16
__device__ __forceinline__ void gld16(const unsigned short* g, unsigned short* l) {
  __builtin_amdgcn_global_load_lds(
      (const __attribute__((address_space(1))) unsigned int*)g,
      (__attribute__((address_space(3))) unsigned int*)l, 16, 0, 0);
}

// ---------------- batched cast fp32 -> bf16 ----------------
__global__ __launch_bounds__(256) void cast3_kernel(const float* __restrict__ a, const float* __restrict__ b,
                                                    const float* __restrict__ c, unsigned short* __restrict__ oa,
                                                    unsigned short* __restrict__ ob, unsigned short* __restrict__ oc,
                                                    int n4) {
  int idx = blockIdx.x * 256 + threadIdx.x;
  if (idx >= n4) return;
  const float* in = (blockIdx.y == 0) ? a : (blockIdx.y == 1) ? b : c;
  unsigned short* out = (blockIdx.y == 0) ? oa : (blockIdx.y == 1) ? ob : oc;
  const float4 v = ((const float4*)in)[idx];
  ushort4 o;
  o.x = f2bf(v.x); o.y = f2bf(v.y); o.z = f2bf(v.z); o.w = f2bf(v.w);
  ((ushort4*)out)[idx] = o;
}

// ---------------- transpose + cast (z-batched pair): in (K x N fp32) -> out (N x K bf16) ----------------
__global__ __launch_bounds__(256) void transpose2_kernel(const float* __restrict__ in0, unsigned short* __restrict__ out0,
                                                         const float* __restrict__ in1, unsigned short* __restrict__ out1,
                                                         int K, int N) {
  __shared__ float tile[64][65];
  const float* in = blockIdx.z ? in1 : in0;
  unsigned short* out = blockIdx.z ? out1 : out0;
  const int kb = blockIdx.x * 64, nb = blockIdx.y * 64;
  const int tid = threadIdx.x;
  const int r = tid >> 4;
  const int c = (tid & 15) * 4;
#pragma unroll
  for (int i = 0; i < 4; i++) {
    const float4 v = *(const float4*)(in + (size_t)(kb + r + i * 16) * N + nb + c);
    tile[r + i * 16][c + 0] = v.x;
    tile[r + i * 16][c + 1] = v.y;
    tile[r + i * 16][c + 2] = v.z;
    tile[r + i * 16][c + 3] = v.w;
  }
  __syncthreads();
#pragma unroll
  for (int i = 0; i < 4; i++) {
    int n = r + i * 16;
    ushort4 o;
    o.x = f2bf(tile[c + 0][n]);
    o.y = f2bf(tile[c + 1][n]);
    o.z = f2bf(tile[c + 2][n]);
    o.w = f2bf(tile[c + 3][n]);
    *(ushort4*)(out + (size_t)(nb + n) * K + kb + c) = o;
  }
}

// ---------------- m97-style GEMM: C(MxN) = A(MxK) @ BT(NxK)^T, bf16, global_load_lds staging ----------------
// LDS layout (16B slots): slot(row, seg) = row*8 + (seg ^ (row&7))  -> 2-way max on ds_read_b128
// Tile: 128 x (NF*32), BK=64. z-batched operand sets.
template <int NF, bool F32OUT>
__global__ __launch_bounds__(256, 2) void gemm_lds(const unsigned short* __restrict__ A0,
                                                   const unsigned short* __restrict__ B0, void* __restrict__ C0,
                                                   const unsigned short* __restrict__ A1,
                                                   const unsigned short* __restrict__ B1, void* __restrict__ C1,
                                                   int M, int N, int K) {
  constexpr int TN = NF * 32;
  __shared__ __align__(16) unsigned short As[128 * 64];
  __shared__ __align__(16) unsigned short Bs[TN * 64];
  const unsigned short* A = blockIdx.z ? A1 : A0;
  const unsigned short* BT = blockIdx.z ? B1 : B0;
  void* C = blockIdx.z ? C1 : C0;

  const int m0 = blockIdx.x * 128, n0 = blockIdx.y * TN;
  const int tid = threadIdx.x;
  const int lane = tid & 63;
  const int w = __builtin_amdgcn_readfirstlane(tid >> 6);  // wave id (uniform)
  const int wm = (w & 1) * 64, wn = (w >> 1) * (TN / 2);
  const int lr = lane & 15, kg = lane >> 4;
  // staging source mapping: lane l -> row w*8 + l/8 (+32*i), source seg (l&7)^(l/8)
  const int lrow = lane >> 3;
  const int lseg = (lane & 7) ^ lrow;

  const unsigned short* Abase = A + (size_t)(m0 + w * 8 + lrow) * K + lseg * 8;
  const unsigned short* Bbase = BT + (size_t)(n0 + w * 8 + lrow) * K + lseg * 8;

  f32x4 acc[4][NF] = {};
  for (int k0 = 0; k0 < K; k0 += 64) {
#pragma unroll
    for (int i = 0; i < 4; i++)
      gld16(Abase + (size_t)(32 * i) * K + k0, As + (32 * i + w * 8) * 64);
#pragma unroll
    for (int i = 0; i < NF; i++)
      gld16(Bbase + (size_t)(32 * i) * K + k0, Bs + (32 * i + w * 8) * 64);
    __syncthreads();
#pragma unroll
    for (int ks = 0; ks < 2; ks++) {
      short8 af[4], bfg[NF];
#pragma unroll
      for (int mi = 0; mi < 4; mi++) {
        int row = wm + mi * 16 + lr;
        af[mi] = *(const short8*)(As + row * 64 + ((ks * 4 + kg) ^ (lr & 7)) * 8);
      }
#pragma unroll
      for (int ni = 0; ni < NF; ni++) {
        int row = wn + ni * 16 + lr;
        bfg[ni] = *(const short8*)(Bs + row * 64 + ((ks * 4 + kg) ^ (lr & 7)) * 8);
      }
#pragma unroll
      for (int mi = 0; mi < 4; mi++)
#pragma unroll
        for (int ni = 0; ni < NF; ni++)
          acc[mi][ni] = __builtin_amdgcn_mfma_f32_16x16x32_bf16(af[mi], bfg[ni], acc[mi][ni], 0, 0, 0);
    }
    __syncthreads();
  }
#pragma unroll
  for (int mi = 0; mi < 4; mi++)
#pragma unroll
    for (int ni = 0; ni < NF; ni++)
#pragma unroll
      for (int r2 = 0; r2 < 4; r2++) {
        int m = m0 + wm + mi * 16 + kg * 4 + r2;
        int n = n0 + wn + ni * 16 + lr;
        float v = acc[mi][ni][r2];
        if (F32OUT)
          ((float*)C)[(size_t)m * N + n] = v;
        else
          ((unsigned short*)C)[(size_t)m * N + n] = f2bf(v);
      }
}

// ---------------- RoPE in-place on bf16 projected Q or K ----------------
__global__ __launch_bounds__(256) void rope_kernel(unsigned short* __restrict__ buf, int nheads, int total) {
  int idx = blockIdx.x * 256 + threadIdx.x;
  if (idx >= total) return;
  int i = idx & 63;
  int h = (idx >> 6) % nheads;
  int row = idx / (64 * nheads);
  int pos = row & 1023;
  float invf = exp2f(-(float)(2 * i) * (13.287712379549449f / 128.f));  // 10000^(-2i/128)
  float ang = (float)pos * invf;
  float s, c;
  __sincosf(ang, &s, &c);
  unsigned short* p = buf + (size_t)row * ((size_t)nheads * 128) + h * 128;
  float x1 = bf2f(p[i]), x2 = bf2f(p[i + 64]);
  p[i] = f2bf(x1 * c - x2 * s);
  p[i + 64] = f2bf(x2 * c + x1 * s);
}

// ---------------- Flash attention: BQ=64 (16 rows/wave), BK=64, D=128 ----------------
__global__ __launch_bounds__(256, 2) void flash_kernel(const unsigned short* __restrict__ Q,
                                                       const unsigned short* __restrict__ Kbuf,
                                                       const unsigned short* __restrict__ Vbuf,
                                                       const float* __restrict__ mask,
                                                       unsigned short* __restrict__ Ctx) {
  __shared__ unsigned short Ks[64][136];
  __shared__ unsigned short Vt[128][64];
  __shared__ unsigned short Ps[4][16][72];
  const int qb = blockIdx.x, h = blockIdx.y, b = blockIdx.z;
  const int hkv = h >> 2;
  const int tid = threadIdx.x, wave = tid >> 6, lane = tid & 63;
  const int lr = lane & 15, kg = lane >> 4;
  const int q0 = qb * 64 + wave * 16;

  short8 qf[4];
  {
    const unsigned short* qp = Q + (size_t)(b * 1024 + q0 + lr) * 4096 + h * 128 + kg * 8;
#pragma unroll
    for (int ks = 0; ks < 4; ks++) qf[ks] = *(const short8*)(qp + ks * 32);
  }
  f32x4 o[8] = {};
  float mrow_[4], lrow_[4];
#pragma unroll
  for (int r2 = 0; r2 < 4; r2++) { mrow_[r2] = -1e30f; lrow_[r2] = 0.f; }
  const float* mbase = mask + (size_t)b * 1024 * 1024;

  for (int k0 = 0; k0 < 1024; k0 += 64) {
    {
      int row = tid >> 4, cc = (tid & 15) * 8;
#pragma unroll
      for (int i = 0; i < 4; i++)
        *(short8*)&Ks[row + i * 16][cc] =
            *(const short8*)(Kbuf + (size_t)(b * 1024 + k0 + row + i * 16) * 1024 + hkv * 128 + cc);
#pragma unroll
      for (int pass = 0; pass < 2; pass++) {
        int kp = (tid >> 4) * 2 + pass * 32;
        int d0 = (tid & 15) * 8;
        short8 v0 = *(const short8*)(Vbuf + (size_t)(b * 1024 + k0 + kp) * 1024 + hkv * 128 + d0);
        short8 v1 = *(const short8*)(Vbuf + (size_t)(b * 1024 + k0 + kp + 1) * 1024 + hkv * 128 + d0);
#pragma unroll
        for (int j = 0; j < 8; j++) {
          int d = d0 + j;
          int kk = kp ^ (((d >> 3) & 7) << 3);
          unsigned int pack = (unsigned int)(unsigned short)v0[j] | ((unsigned int)(unsigned short)v1[j] << 16);
          *(unsigned int*)&Vt[d][kk] = pack;
        }
      }
    }
    __syncthreads();

    f32x4 s[4] = {};
#pragma unroll
    for (int ks = 0; ks < 4; ks++)
#pragma unroll
      for (int nf = 0; nf < 4; nf++) {
        short8 kf = *(const short8*)&Ks[nf * 16 + lr][ks * 32 + kg * 8];
        s[nf] = __builtin_amdgcn_mfma_f32_16x16x32_bf16(qf[ks], kf, s[nf], 0, 0, 0);
      }

    float sv[4][4];
#pragma unroll
    for (int nf = 0; nf < 4; nf++)
#pragma unroll
      for (int r2 = 0; r2 < 4; r2++) {
        float v = s[nf][r2] * 0.08838834764831845f;
        int qq = q0 + kg * 4 + r2;
        int kx = k0 + nf * 16 + lr;
        float mv = mbase[(size_t)qq * 1024 + kx];
        sv[nf][r2] = (mv != 0.f) ? v : -1e9f;
      }

    float rmax[4];
#pragma unroll
    for (int r2 = 0; r2 < 4; r2++) {
      float v = fmaxf(fmaxf(sv[0][r2], sv[1][r2]), fmaxf(sv[2][r2], sv[3][r2]));
#pragma unroll
      for (int off = 1; off < 16; off <<= 1) v = fmaxf(v, __shfl_xor(v, off, 16));
      rmax[r2] = v;
    }
    float alpha[4];
#pragma unroll
    for (int r2 = 0; r2 < 4; r2++) {
      float mnew = fmaxf(mrow_[r2], rmax[r2]);
      alpha[r2] = __expf(mrow_[r2] - mnew);
      mrow_[r2] = mnew;
    }
    float rsum[4] = {0.f, 0.f, 0.f, 0.f};
    unsigned short pb[4][4];
#pragma unroll
    for (int nf = 0; nf < 4; nf++)
#pragma unroll
      for (int r2 = 0; r2 < 4; r2++) {
        float p = __expf(sv[nf][r2] - mrow_[r2]);
        rsum[r2] += p;
        pb[nf][r2] = f2bf(p);
      }
#pragma unroll
    for (int r2 = 0; r2 < 4; r2++) {
      float v = rsum[r2];
#pragma unroll
      for (int off = 1; off < 16; off <<= 1) v += __shfl_xor(v, off, 16);
      lrow_[r2] = lrow_[r2] * alpha[r2] + v;
    }
#pragma unroll
    for (int nf2 = 0; nf2 < 8; nf2++)
#pragma unroll
      for (int r2 = 0; r2 < 4; r2++) o[nf2][r2] *= alpha[r2];

#pragma unroll
    for (int nf = 0; nf < 4; nf++)
#pragma unroll
      for (int r2 = 0; r2 < 4; r2++) Ps[wave][kg * 4 + r2][nf * 16 + lr] = pb[nf][r2];

#pragma unroll
    for (int ks2 = 0; ks2 < 2; ks2++) {
      short8 pf = *(const short8*)&Ps[wave][lr][ks2 * 32 + kg * 8];
#pragma unroll
      for (int nf = 0; nf < 8; nf++) {
        int d = nf * 16 + lr;
        int kk = (ks2 * 32 + kg * 8) ^ (((d >> 3) & 7) << 3);
        short8 vf = *(const short8*)&Vt[d][kk];
        o[nf] = __builtin_amdgcn_mfma_f32_16x16x32_bf16(pf, vf, o[nf], 0, 0, 0);
      }
    }
    __syncthreads();
  }

#pragma unroll
  for (int nf = 0; nf < 8; nf++)
#pragma unroll
    for (int r2 = 0; r2 < 4; r2++) {
      float v = o[nf][r2] / lrow_[r2];
      int qq = q0 + kg * 4 + r2;
      int d = nf * 16 + lr;
      Ctx[(size_t)(b * 1024 + qq) * 4096 + h * 128 + d] = f2bf(v);
    }
}

extern "C" void kernel_launch(void* const* d_in, const int* in_sizes, int n_in,
                              void* d_out, int out_size, void* d_ws, size_t ws_size,
                              hipStream_t stream) {
  const float* query = (const float*)d_in[0];
  const float* key   = (const float*)d_in[1];
  const float* value = (const float*)d_in[2];
  const float* mask  = (const float*)d_in[3];
  const float* wq    = (const float*)d_in[4];
  const float* wk    = (const float*)d_in[5];
  const float* wv    = (const float*)d_in[6];
  const float* wo    = (const float*)d_in[7];
  float* out = (float*)d_out;

  char* ws = (char*)d_ws;
  size_t off = 0;
  auto alloc = [&](size_t elems) {
    unsigned short* p = (unsigned short*)(ws + off);
    off += ((elems * 2 + 255) / 256) * 256;
    return p;
  };
  unsigned short* qbf = alloc((size_t)2048 * 4096);
  unsigned short* kbf = alloc((size_t)2048 * 4096);
  unsigned short* vbf = alloc((size_t)2048 * 4096);
  unsigned short* wqT = alloc((size_t)4096 * 4096);
  unsigned short* wkT = alloc((size_t)1024 * 4096);
  unsigned short* wvT = alloc((size_t)1024 * 4096);
  unsigned short* woT = alloc((size_t)4096 * 4096);
  unsigned short* Qb  = alloc((size_t)2048 * 4096);
  unsigned short* Kb  = alloc((size_t)2048 * 1024);
  unsigned short* Vb  = alloc((size_t)2048 * 1024);
  unsigned short* Ctx = qbf;  // reuse: qbf dead after Q projection

  cast3_kernel<<<dim3(8192, 3), 256, 0, stream>>>(query, key, value, qbf, kbf, vbf, 2048 * 4096 / 4);
  transpose2_kernel<<<dim3(64, 64, 2), 256, 0, stream>>>(wq, wqT, wo, woT, 4096, 4096);
  transpose2_kernel<<<dim3(64, 16, 2), 256, 0, stream>>>(wk, wkT, wv, wvT, 4096, 1024);

  // Q projection: 2048x4096x4096
  gemm_lds<4, false><<<dim3(16, 32, 1), 256, 0, stream>>>(qbf, wqT, Qb, qbf, wqT, Qb, 2048, 4096, 4096);
  // K and V projections batched: 2048x1024x4096 each, TN=64 -> grid 16x16x2 = 512 blocks
  gemm_lds<2, false><<<dim3(16, 16, 2), 256, 0, stream>>>(kbf, wkT, Kb, vbf, wvT, Vb, 2048, 1024, 4096);

  rope_kernel<<<(2048 * 32 * 64) / 256, 256, 0, stream>>>(Qb, 32, 2048 * 32 * 64);
  rope_kernel<<<(2048 * 8 * 64) / 256, 256, 0, stream>>>(Kb, 8, 2048 * 8 * 64);

  flash_kernel<<<dim3(16, 32, 2), 256, 0, stream>>>(Qb, Kb, Vb, mask, Ctx);

  // output projection: 2048x4096x4096, fp32 out
  gemm_lds<4, true><<<dim3(16, 32, 1), 256, 0, stream>>>(Ctx, woT, out, Ctx, woT, out, 2048, 4096, 4096);

  (void)in_sizes; (void)n_in; (void)out_size; (void)ws_size;
}